// Round 10
// baseline (47.900 us; speedup 1.0000x reference)
//
#include <hip/hip_runtime.h>
#include <math.h>

#define SCALE 8
#define PSZ 32

// ---- constant twiddles: W_32^k = cos(2pi k/32) - i sin(2pi k/32), k=0..15 ----
__device__ constexpr float C32[16] = {
     1.000000000000000f,  0.980785280403230f,  0.923879532511287f,  0.831469612302545f,
     0.707106781186548f,  0.555570233019602f,  0.382683432365090f,  0.195090322016128f,
     0.000000000000000f, -0.195090322016128f, -0.382683432365090f, -0.555570233019602f,
    -0.707106781186548f, -0.831469612302545f, -0.923879532511287f, -0.980785280403230f };
__device__ constexpr float S32[16] = {
     0.000000000000000f,  0.195090322016128f,  0.382683432365090f,  0.555570233019602f,
     0.707106781186548f,  0.831469612302545f,  0.923879532511287f,  0.980785280403230f,
     1.000000000000000f,  0.980785280403230f,  0.923879532511287f,  0.831469612302545f,
     0.707106781186548f,  0.555570233019602f,  0.382683432365090f,  0.195090322016128f };

__device__ __forceinline__ constexpr int brev4(int i) {
    return ((i & 1) << 3) | ((i & 2) << 1) | ((i & 4) >> 1) | ((i & 8) >> 3);
}

// in-place 16-point radix-2 DIT FFT, fully unrolled (compile-time indices).
// Twiddle W16^(j*(16/m)) == W32^(j*(32/m)) -> same C32/S32 tables. (R9-verified)
__device__ __forceinline__ void fft16(float re[16], float im[16]) {
#pragma unroll
    for (int i = 0; i < 16; ++i) {
        const int j = brev4(i);
        if (j > i) {
            float t = re[i]; re[i] = re[j]; re[j] = t;
            t = im[i]; im[i] = im[j]; im[j] = t;
        }
    }
#pragma unroll
    for (int s = 1; s <= 4; ++s) {
        const int m = 1 << s;
        const int h = m >> 1;
        const int tstep = 32 >> s;
#pragma unroll
        for (int k = 0; k < 16; k += m) {
#pragma unroll
            for (int j = 0; j < h; ++j) {
                const float wr = C32[j * tstep];
                const float wi = -S32[j * tstep];
                const int a = k + j;
                const int b = k + j + h;
                const float tr = wr * re[b] - wi * im[b];
                const float ti = wr * im[b] + wi * re[b];
                re[b] = re[a] - tr; im[b] = im[a] - ti;
                re[a] = re[a] + tr; im[a] = im[a] + ti;
            }
        }
    }
}

// bf16x2 pack/unpack (round-half-up via +0x8000)
__device__ __forceinline__ unsigned pack_bf2(float hi, float lo) {
    const unsigned uh = __float_as_uint(hi) + 0x8000u;
    const unsigned ul = __float_as_uint(lo) + 0x8000u;
    return (uh & 0xFFFF0000u) | (ul >> 16);
}
__device__ __forceinline__ float bf_hi(unsigned u) { return __uint_as_float(u & 0xFFFF0000u); }
__device__ __forceinline__ float bf_lo(unsigned u) { return __uint_as_float(u << 16); }

// ---- gray precompute: g = w0*R + w1*G + w2*B, vectorized float4 ----
__global__ __launch_bounds__(256) void gray_kernel(
        const float* __restrict__ x, const float* __restrict__ w,
        float* __restrict__ g, int n4, long long HW) {
    const int i = blockIdx.x * 256 + threadIdx.x;
    if (i >= n4) return;
    const float w0 = w[0], w1 = w[1], w2 = w[2];
    const float4 a = reinterpret_cast<const float4*>(x)[i];
    const float4 b = reinterpret_cast<const float4*>(x + HW)[i];
    const float4 c = reinterpret_cast<const float4*>(x + 2 * HW)[i];
    float4 o;
    o.x = w0 * a.x + w1 * b.x + w2 * c.x;
    o.y = w0 * a.y + w1 * b.y + w2 * c.y;
    o.z = w0 * a.z + w1 * b.z + w2 * c.z;
    o.w = w0 * a.w + w1 * b.w + w2 * c.w;
    reinterpret_cast<float4*>(g)[i] = o;
}

// WAVE-PARITY STRUCTURE (R10): a 128-thread block = 4 patches (2 pairs).
// The FFT32 is DIF-split (R9-verified math):
//   even bins  X[2k]   = FFT16( x[i] + x[i+16] )
//   odd bins   X[2k+1] = FFT16( (x[i] - x[i+16]) * W32^i )
// Wave 0 computes the EVEN half of everything, wave 1 the ODD half — in
// both the row and column stages. h = wave id is wave-uniform, so the
// even/odd branch is a scalar branch (no divergence) and every FFT/mask
// index is compile-time (mask weights constant-fold). This halves work per
// wave and doubles wave count vs R9 (12,800 waves), attacking the measured
// wave-starvation (only 6,400 waves for 8,192 slots; occupancy ~30%,
// VALUBusy ~50%). LDS 8.4 KB/block -> 16 blocks/CU -> 100% occupancy cap.
// Row stage: lane (g=lane>>5, r=lane&31) = row r of pair g; patches (2g,2g+1)
// packed as rowA + i*rowB. Parity-h half-spectrum -> Hermitian unpack ->
// bf16x2 LDS slots (stride 33; 2-way bank aliasing only = free).
// Col stage: lane (pl=lane>>4, slot=lane&15) = column slot of patch pl; reads
// all 32 row-spectrum entries, parity-h premix, FFT16, masked log-power with
// parity-h weights; 16-lane shuffle reduce; cross-wave combine via LDS.
template <bool GRAY_PRE>
__global__ __launch_bounds__(128) void hfdft_patch_kernel(
        const float* __restrict__ x, const float* __restrict__ w,
        float* __restrict__ out, int H, int W, int mat_h, int mat_w) {
    __shared__ unsigned cb[4 * 528];   // 4 patches * 528 u32 (bf16x2)
    __shared__ float red[8];           // [patch][parity] partial sums

    const int tid = threadIdx.x;
    const int h = tid >> 6;            // wave id == spectral parity (uniform)
    const int lane = tid & 63;
    const int total = mat_h * mat_w;
    const long long HW = (long long)H * W;
    const int Pbase = blockIdx.x * 4;

    // ================= row stage =================
    {
        const int g = lane >> 5, r = lane & 31;
        int pA = Pbase + 2 * g;
        if (pA > total - 1) pA = total - 1;
        int pB = pA + 1; if (pB > total - 1) pB = total - 1;
        const int phA = pA / mat_w, pwA = pA % mat_w;
        const int phB = pB / mat_w, pwB = pB % mat_w;
        const bool adj = (phA == phB) && (pwB == pwA + 1);
        const int baseA = (phA * SCALE + r) * W + pwA * SCALE;
        const int baseB = (phB * SCALE + r) * W + pwB * SCALE;

        // rowA -> ar[0..31], rowB -> br[0..31] (adj: both from one 40px window)
        float ar[32], br[32];
        if (GRAY_PRE && adj) {
            float win[40];
            const float4* g4 = reinterpret_cast<const float4*>(x + baseA);
#pragma unroll
            for (int q = 0; q < 10; ++q) {
                const float4 v = g4[q];
                win[4 * q + 0] = v.x; win[4 * q + 1] = v.y;
                win[4 * q + 2] = v.z; win[4 * q + 3] = v.w;
            }
#pragma unroll
            for (int i = 0; i < 32; ++i) { ar[i] = win[i]; br[i] = win[i + 8]; }
        } else if (GRAY_PRE) {
#pragma unroll
            for (int i = 0; i < 32; ++i) { ar[i] = x[baseA + i]; br[i] = x[baseB + i]; }
        } else {
            const float w0 = w[0], w1 = w[1], w2 = w[2];
#pragma unroll
            for (int i = 0; i < 32; ++i) {
                ar[i] = w0 * x[baseA + i] + w1 * x[HW + baseA + i] + w2 * x[2 * HW + baseA + i];
                br[i] = w0 * x[baseB + i] + w1 * x[HW + baseB + i] + w2 * x[2 * HW + baseB + i];
            }
        }

        float fr[16], fi[16];
        if (h == 0) {
#pragma unroll
            for (int i = 0; i < 16; ++i) {
                fr[i] = ar[i] + ar[i + 16];
                fi[i] = br[i] + br[i + 16];
            }
        } else {
#pragma unroll
            for (int i = 0; i < 16; ++i) {
                const float dre = ar[i] - ar[i + 16];
                const float dim = br[i] - br[i + 16];
                fr[i] = dre * C32[i] + dim * S32[i];
                fi[i] = dim * C32[i] - dre * S32[i];
            }
        }

        fft16(fr, fi);

        unsigned* cbA = cb + (2 * g) * 528;
        unsigned* cbB = cbA + 528;
        if (h == 0) {
            // X[0]=E[0], X[16]=E[8] both real -> packed slot 0
            cbA[r] = pack_bf2(fr[0], fr[8]);
            cbB[r] = pack_bf2(fi[0], fi[8]);
#pragma unroll
            for (int k2 = 1; k2 <= 7; ++k2) {
                const int e2 = 16 - k2;
                const float far_ = 0.5f * (fr[k2] + fr[e2]);
                const float fai_ = 0.5f * (fi[k2] - fi[e2]);
                const float fbr_ = 0.5f * (fi[k2] + fi[e2]);
                const float fbi_ = 0.5f * (fr[e2] - fr[k2]);
                cbA[(2 * k2) * 33 + r] = pack_bf2(far_, fai_);
                cbB[(2 * k2) * 33 + r] = pack_bf2(fbr_, fbi_);
            }
        } else {
#pragma unroll
            for (int k2 = 0; k2 <= 7; ++k2) {
                const int o2 = 15 - k2;
                const float far_ = 0.5f * (fr[k2] + fr[o2]);
                const float fai_ = 0.5f * (fi[k2] - fi[o2]);
                const float fbr_ = 0.5f * (fi[k2] + fi[o2]);
                const float fbi_ = 0.5f * (fr[o2] - fr[k2]);
                cbA[(2 * k2 + 1) * 33 + r] = pack_bf2(far_, fai_);
                cbB[(2 * k2 + 1) * 33 + r] = pack_bf2(fbr_, fbi_);
            }
        }
    }

    __syncthreads();   // waves cross-consume slots (even+odd) in col stage

    // ================= column stage =================
    {
        const int pl = lane >> 4, slot = lane & 15;
        int p = Pbase + pl;
        if (p > total - 1) p = total - 1;
        const unsigned* cbp = cb + pl * 528 + slot * 33;

        float fr[16], fi[16];
        if (h == 0) {
#pragma unroll
            for (int i = 0; i < 16; ++i) {
                const unsigned u0 = cbp[i], u1 = cbp[i + 16];
                fr[i] = bf_hi(u0) + bf_hi(u1);
                fi[i] = bf_lo(u0) + bf_lo(u1);
            }
        } else {
#pragma unroll
            for (int i = 0; i < 16; ++i) {
                const unsigned u0 = cbp[i], u1 = cbp[i + 16];
                const float dre = bf_hi(u0) - bf_hi(u1);
                const float dim = bf_lo(u0) - bf_lo(u1);
                fr[i] = dre * C32[i] + dim * S32[i];
                fi[i] = dim * C32[i] - dre * S32[i];
            }
        }

        fft16(fr, fi);

        float s0 = 0.0f, s1 = 0.0f;
        if (slot == 0) {
            if (h == 0) {
                // even kr = 0,2,...,16 ; pairs (E[k2], E[16-k2]) (k2=0 -> E[0])
#pragma unroll
                for (int k2 = 0; k2 <= 8; ++k2) {
                    const int kr = 2 * k2;
                    const int b = (k2 == 0) ? 0 : 16 - k2;
                    const float g0r = 0.5f * (fr[k2] + fr[b]);
                    const float g0i = 0.5f * (fi[k2] - fi[b]);
                    const float g1r = 0.5f * (fi[k2] + fi[b]);
                    const float g1i = 0.5f * (fr[b] - fr[k2]);
                    const float w0c = (kr >= 7 ? 1.0f : 0.0f) + ((kr >= 8 && kr <= 15) ? 1.0f : 0.0f);
                    const float w16c = 1.0f + ((kr >= 1 && kr <= 15) ? 1.0f : 0.0f);
                    if (w0c > 0.0f)
                        s0 = fmaf(w0c, __logf(g0r * g0r + g0i * g0i + 1.0f), s0);
                    s1 = fmaf(w16c, __logf(g1r * g1r + g1i * g1i + 1.0f), s1);
                }
            } else {
                // odd kr = 1,3,...,15 ; pairs (O[k2], O[15-k2])
#pragma unroll
                for (int k2 = 0; k2 <= 7; ++k2) {
                    const int kr = 2 * k2 + 1;
                    const int b = 15 - k2;
                    const float g0r = 0.5f * (fr[k2] + fr[b]);
                    const float g0i = 0.5f * (fi[k2] - fi[b]);
                    const float g1r = 0.5f * (fi[k2] + fi[b]);
                    const float g1i = 0.5f * (fr[b] - fr[k2]);
                    const float w0c = (kr >= 7 ? 1.0f : 0.0f) + ((kr >= 8 && kr <= 15) ? 1.0f : 0.0f);
                    const float w16c = 2.0f;   // kr in [1,15]
                    if (w0c > 0.0f)
                        s0 = fmaf(w0c, __logf(g0r * g0r + g0i * g0i + 1.0f), s0);
                    s1 = fmaf(w16c, __logf(g1r * g1r + g1i * g1i + 1.0f), s1);
                }
            }
        } else {
            const float b1f = (slot >= 7) ? 1.0f : 0.0f;
            const float m1f = (slot >= 8) ? 1.0f : 0.0f;
            if (h == 0) {
#pragma unroll
                for (int k2 = 0; k2 < 16; ++k2) {
                    const int kr = 2 * k2;
                    const float lp = __logf(fr[k2] * fr[k2] + fi[k2] * fi[k2] + 1.0f);
                    const float wgt = (kr >= 8 && kr <= 24) ? 2.0f : (b1f + m1f);
                    if (k2 & 1) s1 = fmaf(wgt, lp, s1);
                    else        s0 = fmaf(wgt, lp, s0);
                }
            } else {
#pragma unroll
                for (int k2 = 0; k2 < 16; ++k2) {
                    const int kr = 2 * k2 + 1;
                    const float lp = __logf(fr[k2] * fr[k2] + fi[k2] * fi[k2] + 1.0f);
                    float wgt;
                    if (kr == 7)                   wgt = 1.0f + m1f;
                    else if (kr == 25)             wgt = b1f + 1.0f;
                    else if (kr >= 9 && kr <= 23)  wgt = 2.0f;
                    else                           wgt = b1f + m1f;
                    if (k2 & 1) s1 = fmaf(wgt, lp, s1);
                    else        s0 = fmaf(wgt, lp, s0);
                }
            }
        }

        float s = s0 + s1;
#pragma unroll
        for (int off = 8; off >= 1; off >>= 1) s += __shfl_xor(s, off, 16);
        if (slot == 0) red[pl * 2 + h] = s;
    }

    __syncthreads();

    if (tid < 4) {
        const int p = Pbase + tid;
        if (p < total) out[p] = red[tid * 2] + red[tid * 2 + 1];
    }
}

// 8 blocks x 1024 threads; block b writes its partial max to partial[b]
__global__ __launch_bounds__(1024) void max_kernel(
        const float* __restrict__ sums, int n, float* __restrict__ partial) {
    __shared__ float sm[16];
    float m = 0.0f;  // sums are >= 0
    for (int i = blockIdx.x * 1024 + threadIdx.x; i < n; i += gridDim.x * 1024)
        m = fmaxf(m, sums[i]);
#pragma unroll
    for (int off = 32; off >= 1; off >>= 1) m = fmaxf(m, __shfl_xor(m, off, 64));
    if ((threadIdx.x & 63) == 0) sm[threadIdx.x >> 6] = m;
    __syncthreads();
    if (threadIdx.x == 0) {
#pragma unroll
        for (int i = 1; i < 16; ++i) m = fmaxf(m, sm[i]);
        partial[blockIdx.x] = m;
    }
}

__global__ __launch_bounds__(256) void norm_kernel(
        float* __restrict__ out, int n, const float* __restrict__ partial) {
    const int i = blockIdx.x * 256 + threadIdx.x;
    float m = partial[0];
#pragma unroll
    for (int b = 1; b < 8; ++b) m = fmaxf(m, partial[b]);
    if (i < n) out[i] = out[i] / m;
}

extern "C" void kernel_launch(void* const* d_in, const int* in_sizes, int n_in,
                              void* d_out, int out_size, void* d_ws, size_t ws_size,
                              hipStream_t stream) {
    const float* x = (const float*)d_in[0];
    const float* w = (const float*)d_in[1];
    float* out = (float*)d_out;

    const int HWi = in_sizes[0] / 3;
    const int H = (int)(sqrt((double)HWi) + 0.5);
    const int W = H;
    const long long HW = (long long)H * W;
    const int mat = (int)(sqrt((double)out_size) + 0.5);
    const int total = mat * mat;
    const int blocksA = (total + 3) / 4;   // 4 patches per 128-thread block

    float* partial = (float*)d_ws;                  // 8 floats
    float* gray = (float*)((char*)d_ws + 256);
    const size_t need = 256 + (size_t)HW * 4;

    if (ws_size >= need && (W & 3) == 0) {
        const int n4 = (int)(HW / 4);
        hipLaunchKernelGGL(gray_kernel, dim3((n4 + 255) / 256), dim3(256), 0, stream,
                           x, w, gray, n4, HW);
        hipLaunchKernelGGL((hfdft_patch_kernel<true>), dim3(blocksA), dim3(128), 0, stream,
                           gray, w, out, H, W, mat, mat);
    } else {
        hipLaunchKernelGGL((hfdft_patch_kernel<false>), dim3(blocksA), dim3(128), 0, stream,
                           x, w, out, H, W, mat, mat);
    }
    hipLaunchKernelGGL(max_kernel, dim3(8), dim3(1024), 0, stream, out, total, partial);
    hipLaunchKernelGGL(norm_kernel, dim3((total + 255) / 256), dim3(256), 0, stream,
                       out, total, partial);
}

// Round 11
// 43.647 us; speedup vs baseline: 1.0974x; 1.0974x over previous
//
#include <hip/hip_runtime.h>
#include <math.h>

#define SCALE 8
#define PSZ 32

// ---- constant twiddles: W_32^k = cos(2pi k/32) - i sin(2pi k/32), k=0..15 ----
__device__ constexpr float C32[16] = {
     1.000000000000000f,  0.980785280403230f,  0.923879532511287f,  0.831469612302545f,
     0.707106781186548f,  0.555570233019602f,  0.382683432365090f,  0.195090322016128f,
     0.000000000000000f, -0.195090322016128f, -0.382683432365090f, -0.555570233019602f,
    -0.707106781186548f, -0.831469612302545f, -0.923879532511287f, -0.980785280403230f };
__device__ constexpr float S32[16] = {
     0.000000000000000f,  0.195090322016128f,  0.382683432365090f,  0.555570233019602f,
     0.707106781186548f,  0.831469612302545f,  0.923879532511287f,  0.980785280403230f,
     1.000000000000000f,  0.980785280403230f,  0.923879532511287f,  0.831469612302545f,
     0.707106781186548f,  0.555570233019602f,  0.382683432365090f,  0.195090322016128f };

__device__ __forceinline__ constexpr int brev4(int i) {
    return ((i & 1) << 3) | ((i & 2) << 1) | ((i & 4) >> 1) | ((i & 8) >> 3);
}

// in-place 16-point radix-2 DIT FFT, fully unrolled (R9-verified)
__device__ __forceinline__ void fft16(float re[16], float im[16]) {
#pragma unroll
    for (int i = 0; i < 16; ++i) {
        const int j = brev4(i);
        if (j > i) {
            float t = re[i]; re[i] = re[j]; re[j] = t;
            t = im[i]; im[i] = im[j]; im[j] = t;
        }
    }
#pragma unroll
    for (int s = 1; s <= 4; ++s) {
        const int m = 1 << s;
        const int h = m >> 1;
        const int tstep = 32 >> s;
#pragma unroll
        for (int k = 0; k < 16; k += m) {
#pragma unroll
            for (int j = 0; j < h; ++j) {
                const float wr = C32[j * tstep];
                const float wi = -S32[j * tstep];
                const int a = k + j;
                const int b = k + j + h;
                const float tr = wr * re[b] - wi * im[b];
                const float ti = wr * im[b] + wi * re[b];
                re[b] = re[a] - tr; im[b] = im[a] - ti;
                re[a] = re[a] + tr; im[a] = im[a] + ti;
            }
        }
    }
}

// bf16x2 pack/unpack (round-half-up via +0x8000)
__device__ __forceinline__ unsigned pack_bf2(float hi, float lo) {
    const unsigned uh = __float_as_uint(hi) + 0x8000u;
    const unsigned ul = __float_as_uint(lo) + 0x8000u;
    return (uh & 0xFFFF0000u) | (ul >> 16);
}
__device__ __forceinline__ float bf_hi(unsigned u) { return __uint_as_float(u & 0xFFFF0000u); }
__device__ __forceinline__ float bf_lo(unsigned u) { return __uint_as_float(u << 16); }

// ---- gray precompute: g = w0*R + w1*G + w2*B, vectorized float4 ----
__global__ __launch_bounds__(256) void gray_kernel(
        const float* __restrict__ x, const float* __restrict__ w,
        float* __restrict__ g, int n4, long long HW) {
    const int i = blockIdx.x * 256 + threadIdx.x;
    if (i >= n4) return;
    const float w0 = w[0], w1 = w[1], w2 = w[2];
    const float4 a = reinterpret_cast<const float4*>(x)[i];
    const float4 b = reinterpret_cast<const float4*>(x + HW)[i];
    const float4 c = reinterpret_cast<const float4*>(x + 2 * HW)[i];
    float4 o;
    o.x = w0 * a.x + w1 * b.x + w2 * c.x;
    o.y = w0 * a.y + w1 * b.y + w2 * c.y;
    o.z = w0 * a.z + w1 * b.z + w2 * c.z;
    o.w = w0 * a.w + w1 * b.w + w2 * c.w;
    reinterpret_cast<float4*>(g)[i] = o;
}

// ===================== TILE KERNEL (R11) =====================
// 256-thread block = 2-wide x 8-tall patch tile (16 patches).
// Vertical patch overlap (SCALE=8 vs PSZ=32) means each image row's FFT is
// shared by up to 4 patches: the tile needs only 88 distinct rows instead of
// 16x32=512 row-FFT instances (2.9x less row work, 3x less gray traffic).
//
// Row phase: lanes 0..87 each run ONE packed dual-strip row FFT32 (strips
// pw, pw+1 share a 40px window; strip A + i*strip B), DIF-split into even /
// odd FFT16 passes (R9-verified math), Hermitian-unpacked to bf16x2 and
// written to LDS spec[strip][row][slot] with row stride 17 (writes: stride-17
// across lanes -> conflict-free; col reads: worst 2-way aliasing = free).
// Col phase: 256 tasks = 16 patches x 16 slots, 1:1 lanes. Each lane runs
// R9's verified two-pass (even kr / odd kr) column pipeline on its slot's 32
// rows, masked log-power with Hermitian weights, 16-lane shuffle reduce.
__global__ __launch_bounds__(256) void hfdft_tile_kernel(
        const float* __restrict__ g, float* __restrict__ out,
        int W, int mat_w) {
    __shared__ unsigned spec[2 * 88 * 17];   // [strip][row][slot], 11968 B

    const int tid = threadIdx.x;
    const int row0 = blockIdx.y * 64;        // top pixel row of tile
    const int col0 = blockIdx.x * 16;        // left pixel col of shared window

    // ================= row phase (88 tasks) =================
    if (tid < 88) {
        const int y = tid;
        const float4* g4 = reinterpret_cast<const float4*>(
            g + (size_t)(row0 + y) * W + col0);
        unsigned* sA = spec + y * 17;               // strip 0 (pw)
        unsigned* sB = spec + 88 * 17 + y * 17;     // strip 1 (pw+1)

        // ---- pass 1: even bins ----
        {
            float win[40];
#pragma unroll
            for (int q = 0; q < 10; ++q) {
                const float4 v = g4[q];
                win[4 * q + 0] = v.x; win[4 * q + 1] = v.y;
                win[4 * q + 2] = v.z; win[4 * q + 3] = v.w;
            }
            float er[16], ei[16];
#pragma unroll
            for (int i = 0; i < 16; ++i) {
                er[i] = win[i] + win[i + 16];        // strip A sums
                ei[i] = win[i + 8] + win[i + 24];    // strip B sums
            }
            fft16(er, ei);
            sA[0] = pack_bf2(er[0], er[8]);          // (F(0), F(16)) real pair
            sB[0] = pack_bf2(ei[0], ei[8]);
#pragma unroll
            for (int k2 = 1; k2 <= 7; ++k2) {
                const int e2 = 16 - k2;
                const float far_ = 0.5f * (er[k2] + er[e2]);
                const float fai_ = 0.5f * (ei[k2] - ei[e2]);
                const float fbr_ = 0.5f * (ei[k2] + ei[e2]);
                const float fbi_ = 0.5f * (er[e2] - er[k2]);
                sA[2 * k2] = pack_bf2(far_, fai_);
                sB[2 * k2] = pack_bf2(fbr_, fbi_);
            }
        }

        asm volatile("" ::: "memory");   // keep the two FFT16 passes apart

        // ---- pass 2: odd bins ----
        {
            float win[40];
#pragma unroll
            for (int q = 0; q < 10; ++q) {
                const float4 v = g4[q];
                win[4 * q + 0] = v.x; win[4 * q + 1] = v.y;
                win[4 * q + 2] = v.z; win[4 * q + 3] = v.w;
            }
            float orr[16], oi[16];
#pragma unroll
            for (int i = 0; i < 16; ++i) {
                const float dre = win[i] - win[i + 16];
                const float dim = win[i + 8] - win[i + 24];
                orr[i] = dre * C32[i] + dim * S32[i];
                oi[i]  = dim * C32[i] - dre * S32[i];
            }
            fft16(orr, oi);
#pragma unroll
            for (int k2 = 0; k2 <= 7; ++k2) {
                const int o2 = 15 - k2;
                const float far_ = 0.5f * (orr[k2] + orr[o2]);
                const float fai_ = 0.5f * (oi[k2] - oi[o2]);
                const float fbr_ = 0.5f * (oi[k2] + oi[o2]);
                const float fbi_ = 0.5f * (orr[o2] - orr[k2]);
                sA[2 * k2 + 1] = pack_bf2(far_, fai_);
                sB[2 * k2 + 1] = pack_bf2(fbr_, fbi_);
            }
        }
    }

    __syncthreads();

    // ================= col phase (256 tasks, 1:1 lanes) =================
    {
        const int pl = tid >> 4;          // 0..15 = ph_local*2 + strip
        const int slot = tid & 15;
        const int ph = pl >> 1, strip = pl & 1;
        const unsigned* cbp = spec + strip * (88 * 17) + (ph * 8) * 17 + slot;
        const float b1f = (slot >= 7) ? 1.0f : 0.0f;
        const float m1f = (slot >= 8) ? 1.0f : 0.0f;

        float s0 = 0.0f, s1 = 0.0f;

        // ---- pass 1: even kr ----
        {
            float er[16], ei[16];
#pragma unroll
            for (int i = 0; i < 16; ++i) {
                const unsigned u0 = cbp[i * 17], u1 = cbp[(i + 16) * 17];
                er[i] = bf_hi(u0) + bf_hi(u1);
                ei[i] = bf_lo(u0) + bf_lo(u1);
            }
            fft16(er, ei);
            if (slot == 0) {
#pragma unroll
                for (int k2 = 0; k2 <= 8; ++k2) {
                    const int kr = 2 * k2;
                    const int b = (k2 == 0) ? 0 : 16 - k2;
                    const float g0r = 0.5f * (er[k2] + er[b]);
                    const float g0i = 0.5f * (ei[k2] - ei[b]);
                    const float g1r = 0.5f * (ei[k2] + ei[b]);
                    const float g1i = 0.5f * (er[b] - er[k2]);
                    const float w0c = (kr >= 7 ? 1.0f : 0.0f) + ((kr >= 8 && kr <= 15) ? 1.0f : 0.0f);
                    const float w16c = 1.0f + ((kr >= 1 && kr <= 15) ? 1.0f : 0.0f);
                    if (w0c > 0.0f)
                        s0 = fmaf(w0c, __logf(g0r * g0r + g0i * g0i + 1.0f), s0);
                    s1 = fmaf(w16c, __logf(g1r * g1r + g1i * g1i + 1.0f), s1);
                }
            } else {
#pragma unroll
                for (int k2 = 0; k2 < 16; ++k2) {
                    const int kr = 2 * k2;
                    const float lp = __logf(er[k2] * er[k2] + ei[k2] * ei[k2] + 1.0f);
                    const float wgt = (kr >= 8 && kr <= 24) ? 2.0f : (b1f + m1f);
                    if (k2 & 1) s1 = fmaf(wgt, lp, s1);
                    else        s0 = fmaf(wgt, lp, s0);
                }
            }
        }

        asm volatile("" ::: "memory");   // force pass-2 LDS re-read

        // ---- pass 2: odd kr ----
        {
            float orr[16], oi[16];
#pragma unroll
            for (int i = 0; i < 16; ++i) {
                const unsigned u0 = cbp[i * 17], u1 = cbp[(i + 16) * 17];
                const float dre = bf_hi(u0) - bf_hi(u1);
                const float dim = bf_lo(u0) - bf_lo(u1);
                orr[i] = dre * C32[i] + dim * S32[i];
                oi[i]  = dim * C32[i] - dre * S32[i];
            }
            fft16(orr, oi);
            if (slot == 0) {
#pragma unroll
                for (int k2 = 0; k2 <= 7; ++k2) {
                    const int kr = 2 * k2 + 1;
                    const int b = 15 - k2;
                    const float g0r = 0.5f * (orr[k2] + orr[b]);
                    const float g0i = 0.5f * (oi[k2] - oi[b]);
                    const float g1r = 0.5f * (oi[k2] + oi[b]);
                    const float g1i = 0.5f * (orr[b] - orr[k2]);
                    const float w0c = (kr >= 7 ? 1.0f : 0.0f) + ((kr >= 8 && kr <= 15) ? 1.0f : 0.0f);
                    const float w16c = 2.0f;   // kr in [1,15]
                    if (w0c > 0.0f)
                        s0 = fmaf(w0c, __logf(g0r * g0r + g0i * g0i + 1.0f), s0);
                    s1 = fmaf(w16c, __logf(g1r * g1r + g1i * g1i + 1.0f), s1);
                }
            } else {
#pragma unroll
                for (int k2 = 0; k2 < 16; ++k2) {
                    const int kr = 2 * k2 + 1;
                    const float lp = __logf(orr[k2] * orr[k2] + oi[k2] * oi[k2] + 1.0f);
                    float wgt;
                    if (kr == 7)                   wgt = 1.0f + m1f;
                    else if (kr == 25)             wgt = b1f + 1.0f;
                    else if (kr >= 9 && kr <= 23)  wgt = 2.0f;
                    else                           wgt = b1f + m1f;
                    if (k2 & 1) s1 = fmaf(wgt, lp, s1);
                    else        s0 = fmaf(wgt, lp, s0);
                }
            }
        }

        float s = s0 + s1;
#pragma unroll
        for (int off = 8; off >= 1; off >>= 1) s += __shfl_xor(s, off, 16);
        if (slot == 0)
            out[(blockIdx.y * 8 + ph) * mat_w + blockIdx.x * 2 + strip] = s;
    }
}

// ===================== FALLBACK (R10, proven) =====================
template <bool GRAY_PRE>
__global__ __launch_bounds__(128) void hfdft_patch_kernel(
        const float* __restrict__ x, const float* __restrict__ w,
        float* __restrict__ out, int H, int W, int mat_h, int mat_w) {
    __shared__ unsigned cb[4 * 528];
    __shared__ float red[8];

    const int tid = threadIdx.x;
    const int h = tid >> 6;
    const int lane = tid & 63;
    const int total = mat_h * mat_w;
    const long long HW = (long long)H * W;
    const int Pbase = blockIdx.x * 4;

    {
        const int g = lane >> 5, r = lane & 31;
        int pA = Pbase + 2 * g;
        if (pA > total - 1) pA = total - 1;
        int pB = pA + 1; if (pB > total - 1) pB = total - 1;
        const int phA = pA / mat_w, pwA = pA % mat_w;
        const int phB = pB / mat_w, pwB = pB % mat_w;
        const bool adj = (phA == phB) && (pwB == pwA + 1);
        const int baseA = (phA * SCALE + r) * W + pwA * SCALE;
        const int baseB = (phB * SCALE + r) * W + pwB * SCALE;

        float ar[32], br[32];
        if (GRAY_PRE && adj) {
            float win[40];
            const float4* g4 = reinterpret_cast<const float4*>(x + baseA);
#pragma unroll
            for (int q = 0; q < 10; ++q) {
                const float4 v = g4[q];
                win[4 * q + 0] = v.x; win[4 * q + 1] = v.y;
                win[4 * q + 2] = v.z; win[4 * q + 3] = v.w;
            }
#pragma unroll
            for (int i = 0; i < 32; ++i) { ar[i] = win[i]; br[i] = win[i + 8]; }
        } else if (GRAY_PRE) {
#pragma unroll
            for (int i = 0; i < 32; ++i) { ar[i] = x[baseA + i]; br[i] = x[baseB + i]; }
        } else {
            const float w0 = w[0], w1 = w[1], w2 = w[2];
#pragma unroll
            for (int i = 0; i < 32; ++i) {
                ar[i] = w0 * x[baseA + i] + w1 * x[HW + baseA + i] + w2 * x[2 * HW + baseA + i];
                br[i] = w0 * x[baseB + i] + w1 * x[HW + baseB + i] + w2 * x[2 * HW + baseB + i];
            }
        }

        float fr[16], fi[16];
        if (h == 0) {
#pragma unroll
            for (int i = 0; i < 16; ++i) {
                fr[i] = ar[i] + ar[i + 16];
                fi[i] = br[i] + br[i + 16];
            }
        } else {
#pragma unroll
            for (int i = 0; i < 16; ++i) {
                const float dre = ar[i] - ar[i + 16];
                const float dim = br[i] - br[i + 16];
                fr[i] = dre * C32[i] + dim * S32[i];
                fi[i] = dim * C32[i] - dre * S32[i];
            }
        }

        fft16(fr, fi);

        unsigned* cbA = cb + (2 * g) * 528;
        unsigned* cbB = cbA + 528;
        if (h == 0) {
            cbA[r] = pack_bf2(fr[0], fr[8]);
            cbB[r] = pack_bf2(fi[0], fi[8]);
#pragma unroll
            for (int k2 = 1; k2 <= 7; ++k2) {
                const int e2 = 16 - k2;
                const float far_ = 0.5f * (fr[k2] + fr[e2]);
                const float fai_ = 0.5f * (fi[k2] - fi[e2]);
                const float fbr_ = 0.5f * (fi[k2] + fi[e2]);
                const float fbi_ = 0.5f * (fr[e2] - fr[k2]);
                cbA[(2 * k2) * 33 + r] = pack_bf2(far_, fai_);
                cbB[(2 * k2) * 33 + r] = pack_bf2(fbr_, fbi_);
            }
        } else {
#pragma unroll
            for (int k2 = 0; k2 <= 7; ++k2) {
                const int o2 = 15 - k2;
                const float far_ = 0.5f * (fr[k2] + fr[o2]);
                const float fai_ = 0.5f * (fi[k2] - fi[o2]);
                const float fbr_ = 0.5f * (fi[k2] + fi[o2]);
                const float fbi_ = 0.5f * (fr[o2] - fr[k2]);
                cbA[(2 * k2 + 1) * 33 + r] = pack_bf2(far_, fai_);
                cbB[(2 * k2 + 1) * 33 + r] = pack_bf2(fbr_, fbi_);
            }
        }
    }

    __syncthreads();

    {
        const int pl = lane >> 4, slot = lane & 15;
        int p = Pbase + pl;
        if (p > total - 1) p = total - 1;
        const unsigned* cbp = cb + pl * 528 + slot * 33;

        float fr[16], fi[16];
        if (h == 0) {
#pragma unroll
            for (int i = 0; i < 16; ++i) {
                const unsigned u0 = cbp[i], u1 = cbp[i + 16];
                fr[i] = bf_hi(u0) + bf_hi(u1);
                fi[i] = bf_lo(u0) + bf_lo(u1);
            }
        } else {
#pragma unroll
            for (int i = 0; i < 16; ++i) {
                const unsigned u0 = cbp[i], u1 = cbp[i + 16];
                const float dre = bf_hi(u0) - bf_hi(u1);
                const float dim = bf_lo(u0) - bf_lo(u1);
                fr[i] = dre * C32[i] + dim * S32[i];
                fi[i] = dim * C32[i] - dre * S32[i];
            }
        }

        fft16(fr, fi);

        float s0 = 0.0f, s1 = 0.0f;
        if (slot == 0) {
            if (h == 0) {
#pragma unroll
                for (int k2 = 0; k2 <= 8; ++k2) {
                    const int kr = 2 * k2;
                    const int b = (k2 == 0) ? 0 : 16 - k2;
                    const float g0r = 0.5f * (fr[k2] + fr[b]);
                    const float g0i = 0.5f * (fi[k2] - fi[b]);
                    const float g1r = 0.5f * (fi[k2] + fi[b]);
                    const float g1i = 0.5f * (fr[b] - fr[k2]);
                    const float w0c = (kr >= 7 ? 1.0f : 0.0f) + ((kr >= 8 && kr <= 15) ? 1.0f : 0.0f);
                    const float w16c = 1.0f + ((kr >= 1 && kr <= 15) ? 1.0f : 0.0f);
                    if (w0c > 0.0f)
                        s0 = fmaf(w0c, __logf(g0r * g0r + g0i * g0i + 1.0f), s0);
                    s1 = fmaf(w16c, __logf(g1r * g1r + g1i * g1i + 1.0f), s1);
                }
            } else {
#pragma unroll
                for (int k2 = 0; k2 <= 7; ++k2) {
                    const int kr = 2 * k2 + 1;
                    const int b = 15 - k2;
                    const float g0r = 0.5f * (fr[k2] + fr[b]);
                    const float g0i = 0.5f * (fi[k2] - fi[b]);
                    const float g1r = 0.5f * (fi[k2] + fi[b]);
                    const float g1i = 0.5f * (fr[b] - fr[k2]);
                    const float w0c = (kr >= 7 ? 1.0f : 0.0f) + ((kr >= 8 && kr <= 15) ? 1.0f : 0.0f);
                    const float w16c = 2.0f;
                    if (w0c > 0.0f)
                        s0 = fmaf(w0c, __logf(g0r * g0r + g0i * g0i + 1.0f), s0);
                    s1 = fmaf(w16c, __logf(g1r * g1r + g1i * g1i + 1.0f), s1);
                }
            }
        } else {
            const float b1f = (slot >= 7) ? 1.0f : 0.0f;
            const float m1f = (slot >= 8) ? 1.0f : 0.0f;
            if (h == 0) {
#pragma unroll
                for (int k2 = 0; k2 < 16; ++k2) {
                    const int kr = 2 * k2;
                    const float lp = __logf(fr[k2] * fr[k2] + fi[k2] * fi[k2] + 1.0f);
                    const float wgt = (kr >= 8 && kr <= 24) ? 2.0f : (b1f + m1f);
                    if (k2 & 1) s1 = fmaf(wgt, lp, s1);
                    else        s0 = fmaf(wgt, lp, s0);
                }
            } else {
#pragma unroll
                for (int k2 = 0; k2 < 16; ++k2) {
                    const int kr = 2 * k2 + 1;
                    const float lp = __logf(fr[k2] * fr[k2] + fi[k2] * fi[k2] + 1.0f);
                    float wgt;
                    if (kr == 7)                   wgt = 1.0f + m1f;
                    else if (kr == 25)             wgt = b1f + 1.0f;
                    else if (kr >= 9 && kr <= 23)  wgt = 2.0f;
                    else                           wgt = b1f + m1f;
                    if (k2 & 1) s1 = fmaf(wgt, lp, s1);
                    else        s0 = fmaf(wgt, lp, s0);
                }
            }
        }

        float s = s0 + s1;
#pragma unroll
        for (int off = 8; off >= 1; off >>= 1) s += __shfl_xor(s, off, 16);
        if (slot == 0) red[pl * 2 + h] = s;
    }

    __syncthreads();

    if (tid < 4) {
        const int p = Pbase + tid;
        if (p < total) out[p] = red[tid * 2] + red[tid * 2 + 1];
    }
}

// 8 blocks x 1024 threads; block b writes its partial max to partial[b]
__global__ __launch_bounds__(1024) void max_kernel(
        const float* __restrict__ sums, int n, float* __restrict__ partial) {
    __shared__ float sm[16];
    float m = 0.0f;  // sums are >= 0
    for (int i = blockIdx.x * 1024 + threadIdx.x; i < n; i += gridDim.x * 1024)
        m = fmaxf(m, sums[i]);
#pragma unroll
    for (int off = 32; off >= 1; off >>= 1) m = fmaxf(m, __shfl_xor(m, off, 64));
    if ((threadIdx.x & 63) == 0) sm[threadIdx.x >> 6] = m;
    __syncthreads();
    if (threadIdx.x == 0) {
#pragma unroll
        for (int i = 1; i < 16; ++i) m = fmaxf(m, sm[i]);
        partial[blockIdx.x] = m;
    }
}

__global__ __launch_bounds__(256) void norm_kernel(
        float* __restrict__ out, int n, const float* __restrict__ partial) {
    const int i = blockIdx.x * 256 + threadIdx.x;
    float m = partial[0];
#pragma unroll
    for (int b = 1; b < 8; ++b) m = fmaxf(m, partial[b]);
    if (i < n) out[i] = out[i] / m;
}

extern "C" void kernel_launch(void* const* d_in, const int* in_sizes, int n_in,
                              void* d_out, int out_size, void* d_ws, size_t ws_size,
                              hipStream_t stream) {
    const float* x = (const float*)d_in[0];
    const float* w = (const float*)d_in[1];
    float* out = (float*)d_out;

    const int HWi = in_sizes[0] / 3;
    const int H = (int)(sqrt((double)HWi) + 0.5);
    const int W = H;
    const long long HW = (long long)H * W;
    const int mat = (int)(sqrt((double)out_size) + 0.5);
    const int total = mat * mat;

    float* partial = (float*)d_ws;                  // 8 floats
    float* gray = (float*)((char*)d_ws + 256);
    const size_t need = 256 + (size_t)HW * 4;

    const bool shape_ok = ((mat & 7) == 0) && (W == (mat - 1) * SCALE + PSZ)
                          && (H == W) && ((W & 3) == 0);

    if (shape_ok && ws_size >= need) {
        const int n4 = (int)(HW / 4);
        hipLaunchKernelGGL(gray_kernel, dim3((n4 + 255) / 256), dim3(256), 0, stream,
                           x, w, gray, n4, HW);
        dim3 gridT(mat / 2, mat / 8);
        hipLaunchKernelGGL(hfdft_tile_kernel, gridT, dim3(256), 0, stream,
                           gray, out, W, mat);
    } else if (ws_size >= need && (W & 3) == 0) {
        const int n4 = (int)(HW / 4);
        hipLaunchKernelGGL(gray_kernel, dim3((n4 + 255) / 256), dim3(256), 0, stream,
                           x, w, gray, n4, HW);
        hipLaunchKernelGGL((hfdft_patch_kernel<true>), dim3((total + 3) / 4), dim3(128), 0, stream,
                           gray, w, out, H, W, mat, mat);
    } else {
        hipLaunchKernelGGL((hfdft_patch_kernel<false>), dim3((total + 3) / 4), dim3(128), 0, stream,
                           x, w, out, H, W, mat, mat);
    }
    hipLaunchKernelGGL(max_kernel, dim3(8), dim3(1024), 0, stream, out, total, partial);
    hipLaunchKernelGGL(norm_kernel, dim3((total + 255) / 256), dim3(256), 0, stream,
                       out, total, partial);
}